// Round 3
// baseline (942.853 us; speedup 1.0000x reference)
//
#include <hip/hip_runtime.h>
#include <hip/hip_fp16.h>

#define FDIM 64
#define SB 200   // scan blocks

// ---- GEMM: XWh[r][n][f] = fp16( sum_k X[n][k] * W[r][k][f] ) ----
// block 256 thr = 64-node tile; thread = (ng -> 4 nodes) x (fq -> 4 features).
__global__ __launch_bounds__(256) void xw_gemm(
    const float* __restrict__ X, const float* __restrict__ Wmat,
    __half* __restrict__ XWh, int N, int R)
{
    __shared__ float4 Wl[1024];   // [k=64][fq=16]   16 KB
    __shared__ float4 Xl[1024];   // [node=64][k4=16] 16 KB
    const int tid = threadIdx.x;
    const int fq = tid & 15, ng = tid >> 4;
    const int nbase = blockIdx.x * 64;

#pragma unroll
    for (int i = 0; i < 4; ++i) {
        const int idx = tid + i * 256;          // node*16 + k4
        const int n = nbase + (idx >> 4);
        Xl[idx] = (n < N) ? ((const float4*)(X + (size_t)n * FDIM))[idx & 15]
                          : make_float4(0.f, 0.f, 0.f, 0.f);
    }

    for (int r = 0; r < R; ++r) {
        __syncthreads();
        const float4* Wg = (const float4*)(Wmat + (size_t)r * FDIM * FDIM);
#pragma unroll
        for (int i = 0; i < 4; ++i) Wl[tid + i * 256] = Wg[tid + i * 256];
        __syncthreads();

        float4 acc[4];
#pragma unroll
        for (int i = 0; i < 4; ++i) acc[i] = make_float4(0.f, 0.f, 0.f, 0.f);

#pragma unroll
        for (int k4 = 0; k4 < 16; ++k4) {
            const float4 w0 = Wl[(k4 * 4 + 0) * 16 + fq];
            const float4 w1 = Wl[(k4 * 4 + 1) * 16 + fq];
            const float4 w2 = Wl[(k4 * 4 + 2) * 16 + fq];
            const float4 w3 = Wl[(k4 * 4 + 3) * 16 + fq];
#pragma unroll
            for (int i = 0; i < 4; ++i) {
                const float4 x = Xl[(ng * 4 + i) * 16 + k4];
                acc[i].x += x.x * w0.x + x.y * w1.x + x.z * w2.x + x.w * w3.x;
                acc[i].y += x.x * w0.y + x.y * w1.y + x.z * w2.y + x.w * w3.y;
                acc[i].z += x.x * w0.z + x.y * w1.z + x.z * w2.z + x.w * w3.z;
                acc[i].w += x.x * w0.w + x.y * w1.w + x.z * w2.w + x.w * w3.w;
            }
        }
#pragma unroll
        for (int i = 0; i < 4; ++i) {
            const int n = nbase + ng * 4 + i;
            if (n < N) {
                __half2* o = (__half2*)(XWh + ((size_t)r * N + n) * FDIM + fq * 4);
                o[0] = __floats2half2_rn(acc[i].x, acc[i].y);
                o[1] = __floats2half2_rn(acc[i].z, acc[i].w);
            }
        }
    }
}

// ---- counting sort by dst ----
__global__ __launch_bounds__(256) void hist_kernel(
    const int* __restrict__ dst, int* __restrict__ counts, int E)
{
    int i = blockIdx.x * blockDim.x + threadIdx.x;
    const int stride = gridDim.x * blockDim.x;
    for (; i < E; i += stride) atomicAdd(&counts[dst[i]], 1);
}

__global__ __launch_bounds__(256) void scan_partial(
    const int* __restrict__ counts, int* __restrict__ blockSums, int N, int CH)
{
    __shared__ int sh[256];
    const int b = blockIdx.x, tid = threadIdx.x;
    const int i0 = b * CH, iend = min(i0 + CH, N);
    int s = 0;
    for (int i = i0 + tid; i < iend; i += 256) s += counts[i];
    sh[tid] = s; __syncthreads();
    for (int off = 128; off > 0; off >>= 1) {
        if (tid < off) sh[tid] += sh[tid + off];
        __syncthreads();
    }
    if (tid == 0) blockSums[b] = sh[0];
}

__global__ __launch_bounds__(256) void scan_block(int* blockSums, int nb)
{
    __shared__ int sh[256];
    const int tid = threadIdx.x;
    const int v = (tid < nb) ? blockSums[tid] : 0;
    sh[tid] = v; __syncthreads();
    for (int off = 1; off < 256; off <<= 1) {
        const int t = (tid >= off) ? sh[tid - off] : 0;
        __syncthreads();
        sh[tid] += t;
        __syncthreads();
    }
    if (tid < nb) blockSums[tid] = sh[tid] - v;   // exclusive
}

__global__ __launch_bounds__(64) void scan_final(
    const int* __restrict__ counts, const int* __restrict__ blockSums,
    int* __restrict__ offsets, int* __restrict__ cursors,
    int N, int CH, int E)
{
    const int b = blockIdx.x, lane = threadIdx.x;
    const int i0 = b * CH, iend = min(i0 + CH, N);
    int carry = blockSums[b];
    for (int t = i0; t < iend; t += 64) {
        const int i = t + lane;
        const int cnt = (i < iend) ? counts[i] : 0;
        int v = cnt;
#pragma unroll
        for (int o = 1; o < 64; o <<= 1) {
            const int u = __shfl_up(v, o, 64);
            if (lane >= o) v += u;
        }
        if (i < iend) {
            const int ex = carry + v - cnt;
            offsets[i] = ex; cursors[i] = ex;
        }
        carry += __shfl(v, 63, 64);
    }
    if (b == (int)gridDim.x - 1 && lane == 0) offsets[N] = E;
}

__global__ __launch_bounds__(256) void sort_scatter(
    const int* __restrict__ src, const int* __restrict__ dst,
    const int* __restrict__ etype, const float* __restrict__ A,
    int* __restrict__ cursors, int* __restrict__ wsKey, float* __restrict__ wsA,
    int E, int N)
{
    int i = blockIdx.x * blockDim.x + threadIdx.x;
    const int stride = gridDim.x * blockDim.x;
    for (; i < E; i += stride) {
        const int d = dst[i];
        const int pos = atomicAdd(&cursors[d], 1);
        wsKey[pos] = etype[i] * N + src[i];
        wsA[pos] = A[i];
    }
}

// ---- pull aggregation: one wave per dst node, no atomics ----
__global__ __launch_bounds__(256) void dst_aggregate(
    const __half* __restrict__ XWh, const int* __restrict__ offsets,
    const int* __restrict__ wsKey, const float* __restrict__ wsA,
    float* __restrict__ Y, int N)
{
    const int lane = threadIdx.x & 63;
    const int wave = (int)((blockIdx.x * blockDim.x + threadIdx.x) >> 6);
    const int nWaves = (int)((gridDim.x * blockDim.x) >> 6);
    for (int d = wave; d < N; d += nWaves) {
        const int beg = offsets[d], end = offsets[d + 1];
        float acc = 0.f;
        int e = beg;
        for (; e + 4 <= end; e += 4) {
            const int k0 = wsKey[e + 0], k1 = wsKey[e + 1];
            const int k2 = wsKey[e + 2], k3 = wsKey[e + 3];
            const float a0 = wsA[e + 0], a1 = wsA[e + 1];
            const float a2 = wsA[e + 2], a3 = wsA[e + 3];
            const float v0 = __half2float(XWh[(size_t)k0 * FDIM + lane]);
            const float v1 = __half2float(XWh[(size_t)k1 * FDIM + lane]);
            const float v2 = __half2float(XWh[(size_t)k2 * FDIM + lane]);
            const float v3 = __half2float(XWh[(size_t)k3 * FDIM + lane]);
            acc += a0 * v0; acc += a1 * v1; acc += a2 * v2; acc += a3 * v3;
        }
        for (; e < end; ++e)
            acc += wsA[e] * __half2float(XWh[(size_t)wsKey[e] * FDIM + lane]);
        Y[(size_t)d * FDIM + lane] = acc;
    }
}

extern "C" void kernel_launch(void* const* d_in, const int* in_sizes, int n_in,
                              void* d_out, int out_size, void* d_ws, size_t ws_size,
                              hipStream_t stream)
{
    const float* X     = (const float*)d_in[0];
    const float* Wmat  = (const float*)d_in[1];
    const float* A     = (const float*)d_in[2];
    const int*   src   = (const int*)d_in[3];
    const int*   dst   = (const int*)d_in[4];
    const int*   etype = (const int*)d_in[5];
    float* Y = (float*)d_out;

    const int N = in_sizes[0] / FDIM;            // 100000
    const int R = in_sizes[1] / (FDIM * FDIM);   // 8
    const int E = in_sizes[2];                   // 3200000
    (void)n_in; (void)out_size; (void)ws_size;

    // workspace layout (256B aligned): XWh | wsKey | wsA | counts | offsets | cursors | blockSums
    char* ws = (char*)d_ws;
    size_t off = 0;
    auto take = [&](size_t bytes) { char* p = ws + off; off = (off + bytes + 255) & ~(size_t)255; return p; };
    __half* XWh    = (__half*)take((size_t)R * N * FDIM * sizeof(__half)); // 102.4 MB
    int*    wsKey  = (int*)   take((size_t)E * sizeof(int));               // 12.8 MB
    float*  wsA    = (float*) take((size_t)E * sizeof(float));             // 12.8 MB
    int*    counts = (int*)   take((size_t)N * sizeof(int));
    int*    offs   = (int*)   take((size_t)(N + 1) * sizeof(int));
    int*    curs   = (int*)   take((size_t)N * sizeof(int));
    int*    bsums  = (int*)   take((size_t)SB * sizeof(int));

    const int CH = (N + SB - 1) / SB;

    hipMemsetAsync(counts, 0, (size_t)N * sizeof(int), stream);

    xw_gemm<<<(N + 63) / 64, 256, 0, stream>>>(X, Wmat, XWh, N, R);

    hist_kernel<<<1024, 256, 0, stream>>>(dst, counts, E);
    scan_partial<<<SB, 256, 0, stream>>>(counts, bsums, N, CH);
    scan_block<<<1, 256, 0, stream>>>(bsums, SB);
    scan_final<<<SB, 64, 0, stream>>>(counts, bsums, offs, curs, N, CH, E);
    sort_scatter<<<2048, 256, 0, stream>>>(src, dst, etype, A, curs, wsKey, wsA, E, N);

    dst_aggregate<<<2048, 256, 0, stream>>>(XWh, offs, wsKey, wsA, Y, N);
}

// Round 4
// 556.932 us; speedup vs baseline: 1.6929x; 1.6929x over previous
//
#include <hip/hip_runtime.h>
#include <hip/hip_fp16.h>

#define FDIM 64
#define SB 200   // scan blocks

typedef __attribute__((ext_vector_type(8))) short short8;
typedef __attribute__((ext_vector_type(4))) float float4_;

__device__ __forceinline__ unsigned short f2bf(float x) {
    unsigned u = __float_as_uint(x);
    return (unsigned short)((u + 0x7FFF + ((u >> 16) & 1)) >> 16);   // RNE
}

// ---- MFMA GEMM: XWh[r][n][f] = fp16( X[n][:] @ W[r][:][f] ) ----
// Computes D[m=f][n=node] = (W^T)(X^T) with 16x16x32 bf16 MFMA.
// A-frag (W^T): A[m=lane&15 -> f][k=(lane>>4)*8+j]  from LDS Wt[r][f][k] (k-stride 72)
// B-frag (X)  : B[n=lane&15 -> node][k=(lane>>4)*8+j] from global, bf16-converted
// C/D         : col=lane&15=node, row=(lane>>4)*4+reg=f -> 4 consecutive f per lane
//               -> one 8B fp16 store per (r, ftile).
// Block = 256 thr = 4 waves; each wave owns 4 node-tiles of 16 (block = 256 nodes).
// 2 passes of 4 relations each; Wt LDS = 4*64*72*2B = 36 KB -> 4 blocks/CU.
__global__ __launch_bounds__(256) void xw_gemm_mfma(
    const float* __restrict__ X, const float* __restrict__ Wmat,
    __half* __restrict__ XWh, int N, int R)
{
    __shared__ unsigned short Wt[4 * 64 * 72];
    const int tid  = threadIdx.x;
    const int lane = tid & 63;
    const int wave = tid >> 6;
    const int quad = lane >> 4;
    const int l15  = lane & 15;
    const int blockBase = blockIdx.x * 256;

    // Load B-frags (X rows, bf16) for this wave's 4 node-tiles, reused across all r.
    short8 bfrag[4][2];
    bool tvalid[4];
#pragma unroll
    for (int t = 0; t < 4; ++t) {
        const int tb = blockBase + (wave * 4 + t) * 16;
        tvalid[t] = (tb < N);
        if (tvalid[t]) {
            const float* xp = X + (size_t)(tb + l15) * FDIM + quad * 8;
            const float4 x0 = *(const float4*)(xp);
            const float4 x1 = *(const float4*)(xp + 4);
            const float4 x2 = *(const float4*)(xp + 32);
            const float4 x3 = *(const float4*)(xp + 36);
            short8 b0, b1;
            b0[0]=f2bf(x0.x); b0[1]=f2bf(x0.y); b0[2]=f2bf(x0.z); b0[3]=f2bf(x0.w);
            b0[4]=f2bf(x1.x); b0[5]=f2bf(x1.y); b0[6]=f2bf(x1.z); b0[7]=f2bf(x1.w);
            b1[0]=f2bf(x2.x); b1[1]=f2bf(x2.y); b1[2]=f2bf(x2.z); b1[3]=f2bf(x2.w);
            b1[4]=f2bf(x3.x); b1[5]=f2bf(x3.y); b1[6]=f2bf(x3.z); b1[7]=f2bf(x3.w);
            bfrag[t][0] = b0; bfrag[t][1] = b1;
        } else {
            bfrag[t][0] = (short8)(0); bfrag[t][1] = (short8)(0);
        }
    }

    for (int rp = 0; rp < 2; ++rp) {
        __syncthreads();
        // Stage Wt[r][f][k] = bf16(W[rp*4+r][k][f]); lanes walk k (conflict-free writes).
#pragma unroll
        for (int it = 0; it < 16; ++it) {
            const int idx = it * 256 + tid;       // 0..4095
            const int k  = idx & 63;
            const int f4 = (idx >> 6) & 15;
            const int r  = idx >> 10;
            const float4 w = *(const float4*)(Wmat + (((size_t)(rp * 4 + r) * FDIM + k) * FDIM + f4 * 4));
            const int base = (r * 64 + f4 * 4) * 72 + k;
            Wt[base + 0 * 72] = f2bf(w.x);
            Wt[base + 1 * 72] = f2bf(w.y);
            Wt[base + 2 * 72] = f2bf(w.z);
            Wt[base + 3 * 72] = f2bf(w.w);
        }
        __syncthreads();

#pragma unroll
        for (int t = 0; t < 4; ++t) {
            if (!tvalid[t]) continue;
            const int tb = blockBase + (wave * 4 + t) * 16;
            const int node = tb + l15;
#pragma unroll
            for (int r = 0; r < 4; ++r) {
                __half* orow = XWh + ((size_t)(rp * 4 + r) * N + node) * FDIM;
#pragma unroll
                for (int ft = 0; ft < 4; ++ft) {
                    const int f = ft * 16 + l15;
                    const unsigned short* wp = &Wt[(r * 64 + f) * 72 + quad * 8];
                    const short8 a0 = *(const short8*)(wp);
                    const short8 a1 = *(const short8*)(wp + 32);
                    float4_ acc = {0.f, 0.f, 0.f, 0.f};
                    acc = __builtin_amdgcn_mfma_f32_16x16x32_bf16(a0, bfrag[t][0], acc, 0, 0, 0);
                    acc = __builtin_amdgcn_mfma_f32_16x16x32_bf16(a1, bfrag[t][1], acc, 0, 0, 0);
                    const __half2 h01 = __floats2half2_rn(acc[0], acc[1]);
                    const __half2 h23 = __floats2half2_rn(acc[2], acc[3]);
                    uint2 st;
                    st.x = *(const unsigned*)&h01;
                    st.y = *(const unsigned*)&h23;
                    *(uint2*)(orow + ft * 16 + quad * 4) = st;
                }
            }
        }
    }
}

// ---- counting sort by dst ----
__global__ __launch_bounds__(256) void hist_kernel(
    const int* __restrict__ dst, int* __restrict__ counts, int E)
{
    int i = blockIdx.x * blockDim.x + threadIdx.x;
    const int stride = gridDim.x * blockDim.x;
    for (; i < E; i += stride) atomicAdd(&counts[dst[i]], 1);
}

__global__ __launch_bounds__(256) void scan_partial(
    const int* __restrict__ counts, int* __restrict__ blockSums, int N, int CH)
{
    __shared__ int sh[256];
    const int b = blockIdx.x, tid = threadIdx.x;
    const int i0 = b * CH, iend = min(i0 + CH, N);
    int s = 0;
    for (int i = i0 + tid; i < iend; i += 256) s += counts[i];
    sh[tid] = s; __syncthreads();
    for (int off = 128; off > 0; off >>= 1) {
        if (tid < off) sh[tid] += sh[tid + off];
        __syncthreads();
    }
    if (tid == 0) blockSums[b] = sh[0];
}

__global__ __launch_bounds__(256) void scan_block(int* blockSums, int nb)
{
    __shared__ int sh[256];
    const int tid = threadIdx.x;
    const int v = (tid < nb) ? blockSums[tid] : 0;
    sh[tid] = v; __syncthreads();
    for (int off = 1; off < 256; off <<= 1) {
        const int t = (tid >= off) ? sh[tid - off] : 0;
        __syncthreads();
        sh[tid] += t;
        __syncthreads();
    }
    if (tid < nb) blockSums[tid] = sh[tid] - v;   // exclusive
}

__global__ __launch_bounds__(64) void scan_final(
    const int* __restrict__ counts, const int* __restrict__ blockSums,
    int* __restrict__ offsets, int* __restrict__ cursors,
    int N, int CH, int E)
{
    const int b = blockIdx.x, lane = threadIdx.x;
    const int i0 = b * CH, iend = min(i0 + CH, N);
    int carry = blockSums[b];
    for (int t = i0; t < iend; t += 64) {
        const int i = t + lane;
        const int cnt = (i < iend) ? counts[i] : 0;
        int v = cnt;
#pragma unroll
        for (int o = 1; o < 64; o <<= 1) {
            const int u = __shfl_up(v, o, 64);
            if (lane >= o) v += u;
        }
        if (i < iend) {
            const int ex = carry + v - cnt;
            offsets[i] = ex; cursors[i] = ex;
        }
        carry += __shfl(v, 63, 64);
    }
    if (b == (int)gridDim.x - 1 && lane == 0) offsets[N] = E;
}

__global__ __launch_bounds__(256) void sort_scatter(
    const int* __restrict__ src, const int* __restrict__ dst,
    const int* __restrict__ etype, const float* __restrict__ A,
    int* __restrict__ cursors, int2* __restrict__ wsKeyA, int E, int N)
{
    int i = blockIdx.x * blockDim.x + threadIdx.x;
    const int stride = gridDim.x * blockDim.x;
    for (; i < E; i += stride) {
        const int d = dst[i];
        const int pos = atomicAdd(&cursors[d], 1);
        wsKeyA[pos] = make_int2(etype[i] * N + src[i], __float_as_int(A[i]));
    }
}

// ---- pull aggregation: one wave per dst node; 2 edges per step (half2 lanes),
// unroll 4 -> 8 gathers in flight; no atomics. ----
__global__ __launch_bounds__(256) void dst_aggregate(
    const __half* __restrict__ XWh, const int* __restrict__ offsets,
    const int2* __restrict__ wsKeyA, float* __restrict__ Y, int N)
{
    const int lane = threadIdx.x & 63;
    const int hid  = lane >> 5;          // which edge of the pair
    const int fl   = lane & 31;          // feature-pair index (features 2fl, 2fl+1)
    const int wave = (int)((blockIdx.x * blockDim.x + threadIdx.x) >> 6);
    const int nWaves = (int)((gridDim.x * blockDim.x) >> 6);
    const __half2* XW2 = (const __half2*)XWh;

    for (int d = wave; d < N; d += nWaves) {
        const int beg = offsets[d], end = offsets[d + 1];
        float ax = 0.f, ay = 0.f;
        for (int base = beg; base < end; base += 64) {
            const int idx = base + lane;
            const int2 ka = (idx < end) ? wsKeyA[idx] : make_int2(0, 0);  // a=0 -> no-op
            const int nb = min(64, end - base);
            const int npair = (nb + 1) >> 1;
            int s = 0;
            for (; s + 4 <= npair; s += 4) {
                const int j0 = 2 * s + hid, j1 = j0 + 2, j2 = j0 + 4, j3 = j0 + 6;
                const int k0 = __shfl(ka.x, j0, 64); const int b0 = __shfl(ka.y, j0, 64);
                const int k1 = __shfl(ka.x, j1, 64); const int b1 = __shfl(ka.y, j1, 64);
                const int k2 = __shfl(ka.x, j2, 64); const int b2 = __shfl(ka.y, j2, 64);
                const int k3 = __shfl(ka.x, j3, 64); const int b3 = __shfl(ka.y, j3, 64);
                const __half2 v0 = XW2[(size_t)k0 * 32 + fl];
                const __half2 v1 = XW2[(size_t)k1 * 32 + fl];
                const __half2 v2 = XW2[(size_t)k2 * 32 + fl];
                const __half2 v3 = XW2[(size_t)k3 * 32 + fl];
                const float2 f0 = __half22float2(v0); const float a0 = __int_as_float(b0);
                const float2 f1 = __half22float2(v1); const float a1 = __int_as_float(b1);
                const float2 f2 = __half22float2(v2); const float a2 = __int_as_float(b2);
                const float2 f3 = __half22float2(v3); const float a3 = __int_as_float(b3);
                ax += a0 * f0.x; ay += a0 * f0.y;
                ax += a1 * f1.x; ay += a1 * f1.y;
                ax += a2 * f2.x; ay += a2 * f2.y;
                ax += a3 * f3.x; ay += a3 * f3.y;
            }
            for (; s < npair; ++s) {
                const int j = 2 * s + hid;
                const int k = __shfl(ka.x, j, 64); const int b = __shfl(ka.y, j, 64);
                const __half2 v = XW2[(size_t)k * 32 + fl];
                const float2 f = __half22float2(v); const float a = __int_as_float(b);
                ax += a * f.x; ay += a * f.y;
            }
        }
        ax += __shfl_xor(ax, 32, 64);    // combine even/odd edge halves
        ay += __shfl_xor(ay, 32, 64);
        if (lane < 32) {
            ((float2*)(Y + (size_t)d * FDIM))[fl] = make_float2(ax, ay);
        }
    }
}

extern "C" void kernel_launch(void* const* d_in, const int* in_sizes, int n_in,
                              void* d_out, int out_size, void* d_ws, size_t ws_size,
                              hipStream_t stream)
{
    const float* X     = (const float*)d_in[0];
    const float* Wmat  = (const float*)d_in[1];
    const float* A     = (const float*)d_in[2];
    const int*   src   = (const int*)d_in[3];
    const int*   dst   = (const int*)d_in[4];
    const int*   etype = (const int*)d_in[5];
    float* Y = (float*)d_out;

    const int N = in_sizes[0] / FDIM;            // 100000
    const int R = in_sizes[1] / (FDIM * FDIM);   // 8
    const int E = in_sizes[2];                   // 3200000
    (void)n_in; (void)out_size; (void)ws_size;

    char* ws = (char*)d_ws;
    size_t off = 0;
    auto take = [&](size_t bytes) { char* p = ws + off; off = (off + bytes + 255) & ~(size_t)255; return p; };
    __half* XWh    = (__half*)take((size_t)R * N * FDIM * sizeof(__half)); // 102.4 MB
    int2*   wsKeyA = (int2*)  take((size_t)E * sizeof(int2));              // 25.6 MB
    int*    counts = (int*)   take((size_t)N * sizeof(int));
    int*    offs   = (int*)   take((size_t)(N + 1) * sizeof(int));
    int*    curs   = (int*)   take((size_t)N * sizeof(int));
    int*    bsums  = (int*)   take((size_t)SB * sizeof(int));

    const int CH = (N + SB - 1) / SB;

    hipMemsetAsync(counts, 0, (size_t)N * sizeof(int), stream);

    xw_gemm_mfma<<<(N + 255) / 256, 256, 0, stream>>>(X, Wmat, XWh, N, R);

    hist_kernel<<<1024, 256, 0, stream>>>(dst, counts, E);
    scan_partial<<<SB, 256, 0, stream>>>(counts, bsums, N, CH);
    scan_block<<<1, 256, 0, stream>>>(bsums, SB);
    scan_final<<<SB, 64, 0, stream>>>(counts, bsums, offs, curs, N, CH, E);
    sort_scatter<<<2048, 256, 0, stream>>>(src, dst, etype, A, curs, wsKeyA, E, N);

    dst_aggregate<<<1024, 256, 0, stream>>>(XWh, offs, wsKeyA, Y, N);
}